// Round 5
// baseline (211.876 us; speedup 1.0000x reference)
//
#include <hip/hip_runtime.h>
#include <hip/hip_bf16.h>
#include <math.h>

#define NB 65536
#define DIN 1024
#define NQ 64
#define DOUT 1024

typedef __attribute__((ext_vector_type(8))) short bf16x8;
typedef __attribute__((ext_vector_type(4))) float f32x4;

__device__ __forceinline__ unsigned short f2bf(float f) {
    union { float f; unsigned u; } v; v.f = f;
    unsigned r = (v.u + 0x7fffu + ((v.u >> 16) & 1u)) >> 16;
    return (unsigned short)r;
}

// ---- kP: precompute bf16 weights + per-q constants --------------------------
__global__ __launch_bounds__(256) void kP(const float* __restrict__ W_in,
                                          const float* __restrict__ W_out,
                                          const float* __restrict__ qp,
                                          unsigned short* __restrict__ Wb,
                                          unsigned short* __restrict__ Wob,
                                          float* __restrict__ cp0,
                                          float* __restrict__ cq) {
    int i = blockIdx.x * 256 + threadIdx.x;
    if (i < NQ * DIN)  Wb[i]  = f2bf(W_in[i]);
    if (i < DOUT * NQ) Wob[i] = f2bf(W_out[i]);
    if (i < NQ) {
        cp0[i] = cosf(qp[i * 3 + 0]);
        cq[i]  = sinf(qp[i * 3 + 1]) * cosf(qp[i * 3 + 2]);
    }
}

// ---- kF: fused  out = state(x) @ W_out.T + b_out ----------------------------
// 2048 blocks x 128 threads (2 waves) -> 8 blocks/CU, 16 waves/CU resident.
// Wave owns 16 batch rows. Phase A: GEMM1 (K=1024), 2-deep x prefetch, 1-deep
// Wb fragment prefetch. Epilogue -> wave-private 16x64 bf16 LDS tile.
// Phase B: GEMM2 (K=64), single live accumulator (no spill), 1-deep Wob
// fragment prefetch.
__global__ __launch_bounds__(128) void kF(const float* __restrict__ x,
                                          const unsigned short* __restrict__ Wb,
                                          const float* __restrict__ b_in,
                                          const float* __restrict__ cp0,
                                          const float* __restrict__ cq,
                                          const unsigned short* __restrict__ Wob,
                                          const float* __restrict__ b_out,
                                          float* __restrict__ out) {
    // stride 72 shorts = 144 B -> fragment reads alias banks only 2-way (free)
    __shared__ unsigned short st[2][16][72];

    const int wave = threadIdx.x >> 6;
    const int lane = threadIdx.x & 63;
    const int r  = lane & 15;   // tile row (phase A: batch row; also out-col mod 16)
    const int kg = lane >> 4;   // k-group
    const int row0 = blockIdx.x * 32 + wave * 16;

    // ---------------- Phase A: GEMM1 ----------------
    const float* xrow = x + (size_t)(row0 + r) * DIN + kg * 8;
    const unsigned short* wrow = Wb + (size_t)r * DIN + kg * 8;

    f32x4 acc[4] = {f32x4{0,0,0,0}, f32x4{0,0,0,0}, f32x4{0,0,0,0}, f32x4{0,0,0,0}};

    // 2-deep x prefetch ring
    float4 x0a = *(const float4*)(xrow);
    float4 x0b = *(const float4*)(xrow + 4);
    float4 x1a = *(const float4*)(xrow + 32);
    float4 x1b = *(const float4*)(xrow + 36);
    // 1-deep Wb fragment buffer
    bf16x8 bb[4];
    #pragma unroll
    for (int n = 0; n < 4; n++) bb[n] = *(const bf16x8*)(wrow + n * 16 * DIN);

    for (int k0 = 0; k0 < DIN; k0 += 32) {
        float4 x2a, x2b;
        if (k0 + 64 < DIN) {
            x2a = *(const float4*)(xrow + k0 + 64);
            x2b = *(const float4*)(xrow + k0 + 68);
        }
        bf16x8 bn[4];
        if (k0 + 32 < DIN) {
            #pragma unroll
            for (int n = 0; n < 4; n++)
                bn[n] = *(const bf16x8*)(wrow + n * 16 * DIN + k0 + 32);
        }
        union { bf16x8 v; unsigned u[4]; } a;
        asm("v_cvt_pk_bf16_f32 %0, %1, %2" : "=v"(a.u[0]) : "v"(x0a.x), "v"(x0a.y));
        asm("v_cvt_pk_bf16_f32 %0, %1, %2" : "=v"(a.u[1]) : "v"(x0a.z), "v"(x0a.w));
        asm("v_cvt_pk_bf16_f32 %0, %1, %2" : "=v"(a.u[2]) : "v"(x0b.x), "v"(x0b.y));
        asm("v_cvt_pk_bf16_f32 %0, %1, %2" : "=v"(a.u[3]) : "v"(x0b.z), "v"(x0b.w));
        #pragma unroll
        for (int n = 0; n < 4; n++)
            acc[n] = __builtin_amdgcn_mfma_f32_16x16x32_bf16(a.v, bb[n], acc[n], 0, 0, 0);
        x0a = x1a; x0b = x1b; x1a = x2a; x1b = x2b;
        #pragma unroll
        for (int n = 0; n < 4; n++) bb[n] = bn[n];
    }

    // Quantum epilogue (hw transcendentals), write bf16 state tile to LDS.
    // D layout: col q = n*16+r, row = kg*4+i.
    #pragma unroll
    for (int n = 0; n < 4; n++) {
        int q = n * 16 + r;
        float bi = b_in[q], c0q = cp0[q], c1q = cq[q];
        #pragma unroll
        for (int i = 0; i < 4; i++) {
            float a  = acc[n][i] + bi;
            // tanh(a) = 1 - 2/(exp2(2a*log2e)+1)
            float e2 = __builtin_amdgcn_exp2f(a * 2.8853900817779268f);
            float th = 1.0f - 2.0f * __builtin_amdgcn_rcpf(e2 + 1.0f);
            // cos(th * pi/2) = cos(2*pi * th/4)  (v_cos takes revolutions)
            float s  = __builtin_amdgcn_cosf(th * 0.25f) * c0q + c1q;
            st[wave][kg * 4 + i][q] = f2bf(s);
        }
    }

    __syncthreads();

    // ---------------- Phase B: GEMM2 ----------------
    // A-fragment: lane row = r (wave-local), k(=q) = kg*8+j  /  +32 for a1
    bf16x8 sa0 = *(const bf16x8*)&st[wave][r][kg * 8];
    bf16x8 sa1 = *(const bf16x8*)&st[wave][r][32 + kg * 8];

    const size_t orow = (size_t)(row0 + kg * 4) * DOUT;

    // 1-deep Wob fragment prefetch
    const unsigned short* wp0 = Wob + (size_t)r * NQ + kg * 8;
    bf16x8 wb0 = *(const bf16x8*)(wp0);
    bf16x8 wb1 = *(const bf16x8*)(wp0 + 32);

    #pragma unroll 4
    for (int n = 0; n < 64; n++) {
        bf16x8 wn0, wn1;
        if (n + 1 < 64) {
            const unsigned short* wp = Wob + (size_t)((n + 1) * 16 + r) * NQ + kg * 8;
            wn0 = *(const bf16x8*)(wp);
            wn1 = *(const bf16x8*)(wp + 32);
        }
        f32x4 acc2 = {0.0f, 0.0f, 0.0f, 0.0f};
        acc2 = __builtin_amdgcn_mfma_f32_16x16x32_bf16(sa0, wb0, acc2, 0, 0, 0);
        acc2 = __builtin_amdgcn_mfma_f32_16x16x32_bf16(sa1, wb1, acc2, 0, 0, 0);
        int col = n * 16 + r;
        float bo = b_out[col];
        #pragma unroll
        for (int i = 0; i < 4; i++) {
            out[orow + (size_t)i * DOUT + col] = acc2[i] + bo;
        }
        wb0 = wn0; wb1 = wn1;
    }
}

extern "C" void kernel_launch(void* const* d_in, const int* in_sizes, int n_in,
                              void* d_out, int out_size, void* d_ws, size_t ws_size,
                              hipStream_t stream) {
    const float* x    = (const float*)d_in[0];
    const float* W_in = (const float*)d_in[1];
    const float* b_in = (const float*)d_in[2];
    const float* qp   = (const float*)d_in[3];
    const float* W_out= (const float*)d_in[4];
    const float* b_out= (const float*)d_in[5];
    float* out = (float*)d_out;

    char* ws = (char*)d_ws;
    unsigned short* Wb  = (unsigned short*)(ws);            // 128 KB
    unsigned short* Wob = (unsigned short*)(ws + 131072);   // 128 KB
    float*          cp0 = (float*)(ws + 262144);            // 256 B
    float*          cq  = (float*)(ws + 262400);            // 256 B

    kP<<<(NQ * DIN + 255) / 256, 256, 0, stream>>>(W_in, W_out, qp, Wb, Wob, cp0, cq);
    kF<<<NB / 32, 128, 0, stream>>>(x, Wb, b_in, cp0, cq, Wob, b_out, out);
}

// Round 6
// 162.749 us; speedup vs baseline: 1.3019x; 1.3019x over previous
//
#include <hip/hip_runtime.h>
#include <hip/hip_bf16.h>
#include <math.h>

#define NB 65536
#define DIN 1024
#define NQ 64
#define DOUT 1024

typedef __attribute__((ext_vector_type(8))) short bf16x8;
typedef __attribute__((ext_vector_type(4))) float f32x4;
typedef unsigned short u16;

__device__ __forceinline__ u16 f2bf(float f) {
    union { float f; unsigned u; } v; v.f = f;
    return (u16)((v.u + 0x7fffu + ((v.u >> 16) & 1u)) >> 16);
}

// async global->LDS DMA, 16B per lane. dest = wave-uniform base + lane*16.
__device__ __forceinline__ void gll16(const void* gsrc, void* ldst) {
    __builtin_amdgcn_global_load_lds(
        (const __attribute__((address_space(1))) unsigned int*)gsrc,
        (__attribute__((address_space(3))) unsigned int*)ldst, 16, 0, 0);
}

// ---- kP: bf16 weights in FRAGMENT-MAJOR order + per-q constants -------------
// Wbf : for k-chunk c(32), frag n(4), lane l(64), j(8):
//       Wbf[((c*4+n)*64+l)*8+j] = W_in[n*16+(l&15)][c*32+(l>>4)*8+j]
// Wobf: for n-tile n(64), kfrag kf(2), lane l(64), j(8):
//       Wobf[((n*2+kf)*64+l)*8+j] = W_out[n*16+(l&15)][kf*32+(l>>4)*8+j]
__global__ __launch_bounds__(256) void kP(const float* __restrict__ W_in,
                                          const float* __restrict__ W_out,
                                          const float* __restrict__ qp,
                                          u16* __restrict__ Wbf,
                                          u16* __restrict__ Wobf,
                                          float* __restrict__ cp0,
                                          float* __restrict__ cq) {
    int tid = blockIdx.x * 256 + threadIdx.x;       // 0..65535
    {
        int j = tid & 7, l = (tid >> 3) & 63, n = (tid >> 9) & 3, c = tid >> 11;
        int row = n * 16 + (l & 15);
        int k   = c * 32 + (l >> 4) * 8 + j;
        Wbf[tid] = f2bf(W_in[row * DIN + k]);
    }
    {
        int j = tid & 7, l = (tid >> 3) & 63, kf = (tid >> 9) & 1, n = tid >> 10;
        int col = n * 16 + (l & 15);
        int k   = kf * 32 + (l >> 4) * 8 + j;
        Wobf[tid] = f2bf(W_out[col * NQ + k]);
    }
    if (tid < NQ) {
        cp0[tid] = cosf(qp[tid * 3 + 0]);
        cq[tid]  = sinf(qp[tid * 3 + 1]) * cosf(qp[tid * 3 + 2]);
    }
}

// ---- kF: fused, global_load_lds double-buffered pipeline --------------------
// 1024 blocks x 256 threads (4 waves). Block owns 64 rows; wave owns 16.
__global__ __launch_bounds__(256) void kF(const float* __restrict__ x,
                                          const u16* __restrict__ Wbf,
                                          const float* __restrict__ b_in,
                                          const float* __restrict__ cp0,
                                          const float* __restrict__ cq,
                                          const u16* __restrict__ Wobf,
                                          const float* __restrict__ b_out,
                                          float* __restrict__ out) {
    // [0,16384): x dbuf [2][64][32] f32 (XOR-swizzled rows)  OR  Wob dbuf [2][4096] u16
    // [16384,24576): Wb dbuf [2][2048] u16 (fragment-major)
    __shared__ __align__(16) char smem[24576];
    __shared__ u16 st[4][16][72];   // state tile, stride 72 -> conflict-benign

    float* xs = (float*)smem;
    u16*  wbs = (u16*)(smem + 16384);

    const int tid = threadIdx.x;
    const int w = tid >> 6, l = tid & 63;
    const int r = l & 15, kg = l >> 4;
    const int row0 = blockIdx.x * 64;

    // x staging: issue j covers rows j*32+w*8+(l>>3); source slot pre-swizzled
    // so linear LDS dest gives LDS[row][s] = x[row][(s^(row&7))*4 ..+4]
    const int srow  = (w << 3) + (l >> 3);             // j=0 row
    const int sslot = (l & 7) ^ (l >> 3);              // (destslot ^ row&7)
    const float* xsrc0 = x + (size_t)(row0 + srow) * DIN + sslot * 4;
    const float* xsrc1 = xsrc0 + (size_t)32 * DIN;
    const int wl8 = (w * 64 + l) * 8;                  // fragment-major lane offset

    f32x4 acc[4] = {f32x4{0,0,0,0}, f32x4{0,0,0,0}, f32x4{0,0,0,0}, f32x4{0,0,0,0}};

    // ---------------- prologue: stage chunk 0 ----------------
    gll16(xsrc0, smem + (w << 10));
    gll16(xsrc1, smem + 4096 + (w << 10));
    gll16(Wbf + wl8, smem + 16384 + (w << 10));
    asm volatile("s_waitcnt vmcnt(0)" ::: "memory");
    __syncthreads();

    // ---------------- Phase A: GEMM1, 32 chunks of BK=32 ----------------
    const int rowl = w * 16 + r;
    const int sw = r & 7;                              // read-side XOR
    #pragma unroll 2
    for (int t = 0; t < 32; ++t) {
        const int cur = t & 1;
        if (t < 31) {                                  // stage next chunk
            const int nk = (t + 1) * 32;
            char* xb = smem + (cur ^ 1) * 8192;
            gll16(xsrc0 + nk, xb + (w << 10));
            gll16(xsrc1 + nk, xb + 4096 + (w << 10));
            gll16(Wbf + (size_t)(t + 1) * 2048 + wl8,
                  smem + 16384 + (cur ^ 1) * 4096 + (w << 10));
        } else {                                       // stage Wob chunk 0 -> buf0
            gll16(Wobf + wl8, smem + (w << 10));
            gll16(Wobf + 2048 + wl8, smem + 4096 + (w << 10));
        }
        // compute current chunk
        const float* xr = xs + cur * 2048 + rowl * 32;
        float4 xa = *(const float4*)(xr + (((kg * 2) ^ sw) * 4));
        float4 xb = *(const float4*)(xr + (((kg * 2 + 1) ^ sw) * 4));
        union { bf16x8 v; unsigned u[4]; } a;
        asm("v_cvt_pk_bf16_f32 %0, %1, %2" : "=v"(a.u[0]) : "v"(xa.x), "v"(xa.y));
        asm("v_cvt_pk_bf16_f32 %0, %1, %2" : "=v"(a.u[1]) : "v"(xa.z), "v"(xa.w));
        asm("v_cvt_pk_bf16_f32 %0, %1, %2" : "=v"(a.u[2]) : "v"(xb.x), "v"(xb.y));
        asm("v_cvt_pk_bf16_f32 %0, %1, %2" : "=v"(a.u[3]) : "v"(xb.z), "v"(xb.w));
        const u16* wbuf = wbs + cur * 2048;
        #pragma unroll
        for (int n = 0; n < 4; ++n) {
            bf16x8 b = *(const bf16x8*)(wbuf + (n * 64 + l) * 8);
            acc[n] = __builtin_amdgcn_mfma_f32_16x16x32_bf16(a.v, b, acc[n], 0, 0, 0);
        }
        asm volatile("s_waitcnt vmcnt(0)" ::: "memory");
        __syncthreads();
    }

    // ---------------- quantum epilogue -> st (wave-private) ----------------
    #pragma unroll
    for (int n = 0; n < 4; ++n) {
        int q = n * 16 + r;
        float bi = b_in[q], c0q = cp0[q], c1q = cq[q];
        #pragma unroll
        for (int i = 0; i < 4; ++i) {
            float av = acc[n][i] + bi;
            float e2 = __builtin_amdgcn_exp2f(av * 2.8853900817779268f);
            float th = 1.0f - 2.0f * __builtin_amdgcn_rcpf(e2 + 1.0f);
            float s  = __builtin_amdgcn_cosf(th * 0.25f) * c0q + c1q;
            st[w][kg * 4 + i][q] = f2bf(s);
        }
    }
    __syncthreads();

    // ---------------- Phase B: GEMM2, 16 chunks of 4 n-tiles ----------------
    bf16x8 sa0 = *(const bf16x8*)&st[w][r][kg * 8];
    bf16x8 sa1 = *(const bf16x8*)&st[w][r][32 + kg * 8];
    const u16* wos = (const u16*)smem;                 // [2][4096]
    const size_t orow = (size_t)(row0 + w * 16 + kg * 4) * DOUT;

    #pragma unroll 2
    for (int c = 0; c < 16; ++c) {
        const int cur = c & 1;
        if (c < 15) {                                  // stage next Wob chunk
            char* ob = smem + (cur ^ 1) * 8192;
            const u16* src = Wobf + (size_t)(c + 1) * 4096 + wl8;
            gll16(src, ob + (w << 10));
            gll16(src + 2048, ob + 4096 + (w << 10));
        }
        const u16* buf = wos + cur * 4096;
        #pragma unroll
        for (int n = 0; n < 4; ++n) {
            bf16x8 b0 = *(const bf16x8*)(buf + ((n * 2 + 0) * 64 + l) * 8);
            bf16x8 b1 = *(const bf16x8*)(buf + ((n * 2 + 1) * 64 + l) * 8);
            f32x4 a2 = {0.0f, 0.0f, 0.0f, 0.0f};
            a2 = __builtin_amdgcn_mfma_f32_16x16x32_bf16(sa0, b0, a2, 0, 0, 0);
            a2 = __builtin_amdgcn_mfma_f32_16x16x32_bf16(sa1, b1, a2, 0, 0, 0);
            int col = (c * 4 + n) * 16 + r;
            float bo = b_out[col];
            #pragma unroll
            for (int i = 0; i < 4; ++i)
                out[orow + (size_t)i * DOUT + col] = a2[i] + bo;
        }
        asm volatile("s_waitcnt vmcnt(0)" ::: "memory");
        __syncthreads();
    }
}

extern "C" void kernel_launch(void* const* d_in, const int* in_sizes, int n_in,
                              void* d_out, int out_size, void* d_ws, size_t ws_size,
                              hipStream_t stream) {
    const float* x    = (const float*)d_in[0];
    const float* W_in = (const float*)d_in[1];
    const float* b_in = (const float*)d_in[2];
    const float* qp   = (const float*)d_in[3];
    const float* W_out= (const float*)d_in[4];
    const float* b_out= (const float*)d_in[5];
    float* out = (float*)d_out;

    char* ws = (char*)d_ws;
    u16*   Wbf  = (u16*)(ws);              // 128 KB fragment-major W_in
    u16*   Wobf = (u16*)(ws + 131072);     // 128 KB fragment-major W_out
    float* cp0  = (float*)(ws + 262144);   // 256 B
    float* cq   = (float*)(ws + 262400);   // 256 B

    kP<<<256, 256, 0, stream>>>(W_in, W_out, qp, Wbf, Wobf, cp0, cq);
    kF<<<NB / 64, 256, 0, stream>>>(x, Wbf, b_in, cp0, cq, Wobf, b_out, out);
}